// Round 1
// baseline (2876.223 us; speedup 1.0000x reference)
//
#include <hip/hip_runtime.h>
#include <cmath>

// ---------------- problem constants ----------------
#define DDIM   20
#define PVOL   8000      // 20^3
#define PADV   26
#define PADA   676       // 26^2
#define PADVOL 17576     // 26^3
#define CIN    144
#define COUT   72
#define TAPS   343
#define MCH    8

// ---------------- ws float-offset layout ----------------
#define OFF_TPC   0        // 81 floats  (TPC l=0:9 @0, l=1:27 @9, l=2:45 @36)
#define OFF_CG    81       // 1225 floats, 19 tensors
#define OFF_Y     1306     // 25*343 floats, [l^2+m][t]
#define OFF_RAD   9881     // 3*343
#define OFF_BASIS 10910    // 266511
#define CONST_RESV 277504
#define OFF_XP    ((size_t)CONST_RESV)
#define XP_FLOATS ((size_t)2*CIN*PADVOL)          // 5,061,888
#define OFF_K     (OFF_XP + XP_FLOATS)            // 5,339,392
#define K_FLOATS  ((size_t)COUT*CIN*TAPS)         // 3,556,224
#define OFF_STATS (OFF_K + K_FLOATS)              // 8,895,616

// 19 basis-CG tasks (pair order (lo,li) = 00,01,02,10,11,12,20,21,22)
static __device__ const int T_LO[19]   = {0,0,0,1, 1,1,1, 1,1,1, 2, 2,2,2, 2,2,2,2,2};
static __device__ const int T_LI[19]   = {0,1,2,0, 1,1,1, 2,2,2, 0, 1,1,1, 2,2,2,2,2};
static __device__ const int T_L [19]   = {0,1,2,1, 0,1,2, 1,2,3, 2, 1,2,3, 0,1,2,3,4};
static __device__ const int T_CGOFF[19]= {0,1,10,35, 44,53,80, 125,170,245, 350, 375,420,495, 600,625,700,825,1000};
static __device__ const int PAIR_BOFF[9] = {0,1029,4116,9261,12348,40131,86436,91581,137886};

struct WPtrs { const float* p[9]; };

// ---------------- device helpers (fp64) ----------------
__device__ inline double d_fact(int n){ double r=1.0; for(int i=2;i<=n;++i) r*=(double)i; return r; }

__device__ double d_su2cg(int j1,int j2,int j3,int m1,int m2,int m3){
  if(m1+m2!=m3) return 0.0;
  if(j3 < abs(j1-j2) || j3 > j1+j2) return 0.0;
  double pref = sqrt((2.0*j3+1.0)*d_fact(j3+j1-j2)*d_fact(j3-j1+j2)*d_fact(j1+j2-j3)/d_fact(j1+j2+j3+1));
  pref *= sqrt(d_fact(j3+m3)*d_fact(j3-m3)*d_fact(j1-m1)*d_fact(j1+m1)*d_fact(j2-m2)*d_fact(j2+m2));
  double s=0.0;
  for(int k=0;k<=j1+j2+j3;++k){
    int d1=j1+j2-j3-k, d2=j1-m1-k, d3=j2+m2-k, d4=j3-j2+m1+k, d5=j3-j1-m2+k;
    if(d1>=0&&d2>=0&&d3>=0&&d4>=0&&d5>=0)
      s += ((k&1)?-1.0:1.0)/(d_fact(k)*d_fact(d1)*d_fact(d2)*d_fact(d3)*d_fact(d4)*d_fact(d5));
  }
  return pref*s;
}

// nonzero entries of row r of u_c2r(l); returns count (<=2)
__device__ inline int d_urow(int l, int r, int* col, double* ure, double* uim){
  const double is2 = 0.7071067811865476;
  if(r==l){ col[0]=l; ure[0]=1.0; uim[0]=0.0; return 1; }
  if(r>l){ int m=r-l; double sg=(m&1)?-1.0:1.0;
    col[0]=l+m; ure[0]=sg*is2; uim[0]=0.0;
    col[1]=l-m; ure[1]=is2;    uim[1]=0.0; return 2; }
  int m=l-r;
  col[0]=l-m; ure[0]=0.0; uim[0]=is2;
  col[1]=l+m; ure[1]=0.0; uim[1]=-(((m&1)?-1.0:1.0))*is2;
  return 2;
}

__device__ void d_sph(double gx,double gy,double gz,double Y[25]){
  const double PI_ = 3.14159265358979323846;
  double r = sqrt(gx*gx+gy*gy+gz*gz);
  const double eps=1e-9;
  double ct = (r>eps)? gz/fmax(r,eps) : 1.0;
  double phi = atan2(gy,gx);
  double st2 = 1.0-ct*ct; if(st2<0.0) st2=0.0;
  double st = sqrt(st2);
  double P[5][5];
  P[0][0]=1.0;
  for(int m=1;m<=4;++m){
    double dfac=1.0; for(int k=1;k<2*m;k+=2) dfac*=(double)k;
    double stm=1.0; for(int k=0;k<m;++k) stm*=st;
    P[m][m] = ((m&1)?-1.0:1.0)*dfac*stm;
  }
  for(int m=0;m<4;++m) P[m+1][m] = ct*(2*m+1)*P[m][m];
  for(int m=0;m<=4;++m)
    for(int l=m+2;l<=4;++l)
      P[l][m] = ((2*l-1)*ct*P[l-1][m] - (l+m-1)*P[l-2][m])/(double)(l-m);
  int idx=0;
  for(int l=0;l<=4;++l){
    double arr[9];
    for(int k=0;k<2*l+1;++k) arr[k]=0.0;
    for(int m=0;m<=l;++m){
      double N = sqrt((2.0*l+1.0)/(4.0*PI_)*d_fact(l-m)/d_fact(l+m));
      if(m==0) arr[l] = N*P[l][0];
      else{
        arr[l+m]=sqrt(2.0)*N*P[l][m]*cos(m*phi);
        arr[l-m]=sqrt(2.0)*N*P[l][m]*sin(m*phi);
      }
    }
    if(l>0 && !(r>eps)) for(int k=0;k<2*l+1;++k) arr[k]=0.0;
    for(int k=0;k<2*l+1;++k) Y[idx++]=arr[k];
  }
}

// ---------------- kernel 1: CG tables + TPC + Y + RAD ----------------
__global__ __launch_bounds__(256) void gen_cg_kernel(float* __restrict__ consts){
  int task = blockIdx.x, tid = threadIdx.x;
  if(task==22){
    for(int t=tid; t<343; t+=256){
      int ix=t/49, iy=(t/7)%7, iz=t%7;
      double gx=ix-3, gy=iy-3, gz=iz-3;
      double Y[25]; d_sph(gx,gy,gz,Y);
      for(int k=0;k<25;++k) consts[OFF_Y + k*343 + t] = (float)Y[k];
      double r = sqrt(gx*gx+gy*gy+gz*gz);
      for(int j=0;j<3;++j){
        double d = r - 1.5*j;
        consts[OFF_RAD + j*343 + t] = (r<=3.5)? (float)exp(-0.5*d*d) : 0.0f;
      }
    }
    return;
  }
  int j1,j2,j3,outOff;
  if(task<19){ j1=T_LI[task]; j2=T_L[task]; j3=T_LO[task]; outOff = OFF_CG + T_CGOFF[task]; }
  else { int l=task-19; j1=1; j2=1; j3=l; outOff = (l==0)?0:((l==1)?9:36); }
  int n1=2*j1+1, n2=2*j2+1, n3=2*j3+1;
  int cnt = n1*n2*n3;  // <=225
  __shared__ double Cc[225];
  for(int e=tid; e<cnt; e+=256){
    int m=e/(n2*n3), n=(e/n3)%n2, c=e%n3;
    Cc[e] = d_su2cg(j1,j2,j3, m-j1, n-j2, c-j3);
  }
  __syncthreads();
  double tre=0.0, tim=0.0;
  int e = tid;
  if(e<cnt){
    int a=e/(n1*n2), i=(e/n2)%n1, jj=e%n2;
    int c3[2]; double r3[2], q3[2]; int nc3=d_urow(j3,a,c3,r3,q3);
    int c1[2]; double r1[2], q1[2]; int nc1=d_urow(j1,i,c1,r1,q1);
    int c2[2]; double r2[2], q2[2]; int nc2=d_urow(j2,jj,c2,r2,q2);
    for(int ic=0; ic<nc3; ++ic)
      for(int im=0; im<nc1; ++im)
        for(int in_=0; in_<nc2; ++in_){
          double cc = Cc[(c1[im]*n2 + c2[in_])*n3 + c3[ic]];
          if(cc==0.0) continue;
          double ar=r3[ic], ai=q3[ic];
          double br=r1[im], bi=-q1[im];       // conj
          double cr=r2[in_], cim=-q2[in_];    // conj
          double abr = ar*br - ai*bi, abi = ar*bi + ai*br;
          double zr = abr*cr - abi*cim, zi = abr*cim + abi*cr;
          tre += zr*cc; tim += zi*cc;
        }
  }
  __shared__ double mre[256], mim[256];
  mre[tid]=fabs(tre); mim[tid]=fabs(tim);
  __syncthreads();
  for(int s=128;s>0;s>>=1){ if(tid<s){ mre[tid]=fmax(mre[tid],mre[tid+s]); mim[tid]=fmax(mim[tid],mim[tid+s]); } __syncthreads(); }
  bool useim = mim[0] > mre[0];
  if(e<cnt) consts[outOff + e] = (float)(useim? tim : tre);
}

// ---------------- kernel 2: basis assembly + norm ----------------
__global__ __launch_bounds__(256) void gen_basis_kernel(float* __restrict__ consts){
  int task = blockIdx.x/3, j = blockIdx.x%3, tid=threadIdx.x;
  int lo=T_LO[task], li=T_LI[task], l=T_L[task];
  int A=2*lo+1, I=2*li+1, n2=2*l+1;
  int l_idx = l - abs(lo-li);
  const float* T = consts + OFF_CG + T_CGOFF[task];
  const float* Yl = consts + OFF_Y + l*l*343;
  const float* Rj = consts + OFF_RAD + j*343;
  float* out = consts + OFF_BASIS + PAIR_BOFF[lo*3+li] + (size_t)((l_idx*3 + j)*A*I)*343;
  int N = A*I*343;
  double ssq = 0.0;
  for(int e=tid; e<N; e+=256){
    int ai = e/343, t = e%343;
    double ang = 0.0;
    for(int m=0;m<n2;++m) ang += (double)T[ai*n2+m] * (double)Yl[m*343+t];
    double val = ang * (double)Rj[t];
    out[e] = (float)val;
    ssq += val*val;
  }
  __shared__ double red[256];
  red[tid]=ssq; __syncthreads();
  for(int s=128;s>0;s>>=1){ if(tid<s) red[tid]+=red[tid+s]; __syncthreads(); }
  double nrm = sqrt(red[0]);
  float scale = (nrm>1e-12)? (float)(1.0/nrm) : 1.0f;
  for(int e=tid; e<N; e+=256) out[e] *= scale;
}

// ---------------- kernel 3: build padded xin ----------------
__global__ __launch_bounds__(256) void build_xin_kernel(const float* __restrict__ x,
    const float* __restrict__ consts, float* __restrict__ xp){
  int id = blockIdx.x*256 + threadIdx.x;
  if(id >= 2*MCH*PVOL) return;
  int p = id % PVOL; int u = (id/PVOL)%MCH; int b = id/(MCH*PVOL);
  int xi=p/400, rr=p%400, yi=rr/20, zi=rr%20;
  size_t pb = (size_t)(xi+3)*PADA + (size_t)(yi+3)*PADV + (zi+3);
  const float* xb = x + (size_t)b*COUT*PVOL + p;
  float s  = xb[(size_t)u*PVOL];
  float vv[3], qq[5];
  for(int i=0;i<3;++i) vv[i] = xb[(size_t)(8+u*3+i)*PVOL];
  for(int i=0;i<5;++i) qq[i] = xb[(size_t)(32+u*5+i)*PVOL];
  const float* T0 = consts + 0;
  const float* T1 = consts + 9;
  const float* T2 = consts + 36;
  float i0=0.f, i1[3]={0,0,0}, i2[5]={0,0,0,0,0};
  for(int i=0;i<3;++i) for(int jj=0;jj<3;++jj){
    float vij = vv[i]*vv[jj];
    i0 += T0[i*3+jj]*vij;
    for(int a=0;a<3;++a) i1[a] += T1[(a*3+i)*3+jj]*vij;
    for(int a=0;a<5;++a) i2[a] += T2[(a*3+i)*3+jj]*vij;
  }
  float* o = xp + (size_t)b*CIN*PADVOL + pb;
  o[(size_t)u*PADVOL] = s;
  o[(size_t)(8+u)*PADVOL] = i0;
  for(int i=0;i<3;++i) o[(size_t)(16+u*3+i)*PADVOL] = vv[i];
  for(int a=0;a<3;++a) o[(size_t)(40+u*3+a)*PADVOL] = i1[a];
  for(int i=0;i<5;++i) o[(size_t)(64+u*5+i)*PADVOL] = qq[i];
  for(int a=0;a<5;++a) o[(size_t)(104+u*5+a)*PADVOL] = i2[a];
}

// ---------------- kernel 4: build K ----------------
__global__ __launch_bounds__(256) void build_K_kernel(WPtrs W,
    const float* __restrict__ consts, float* __restrict__ Kf){
  size_t idx = (size_t)blockIdx.x*256 + threadIdx.x;
  if(idx >= K_FLOATS) return;
  int t = (int)(idx % TAPS);
  int rc = (int)(idx / TAPS);
  int ci = rc % CIN, co = rc / CIN;
  int lo,u,a;
  if(co<8){ lo=0; u=co; a=0; }
  else if(co<32){ lo=1; u=(co-8)/3; a=(co-8)%3; }
  else { lo=2; u=(co-32)/5; a=(co-32)%5; }
  int li,vv,i;
  if(ci<16){ li=0; vv=ci; i=0; }
  else if(ci<64){ li=1; vv=(ci-16)/3; i=(ci-16)%3; }
  else { li=2; vv=(ci-64)/5; i=(ci-64)%5; }
  int pair = lo*3+li;
  int nl = 2*min(lo,li)+1;
  int A = 2*lo+1, I = 2*li+1;
  const float* bp = consts + OFF_BASIS + PAIR_BOFF[pair];
  const float* wp = W.p[pair];
  float acc = 0.f;
  for(int lk=0; lk<nl; ++lk)
    for(int j=0;j<3;++j)
      acc = fmaf(wp[((u*16+vv)*nl+lk)*3+j],
                 bp[(size_t)(((lk*3+j)*A + a)*I + i)*343 + t], acc);
  Kf[idx] = acc;
}

// ---------------- kernel 5: conv ----------------
#define NCO 6
__global__ __launch_bounds__(256) void conv_kernel(const float* __restrict__ xp,
    const float* __restrict__ Kf, float* __restrict__ y){
  int p = blockIdx.x*256 + threadIdx.x;
  int co0 = blockIdx.y*NCO;
  int b = blockIdx.z;
  if(p >= PVOL) return;
  int xc = p/400, rr = p%400, yc = rr/20, zc = rr%20;
  const float* xb = xp + (size_t)b*CIN*PADVOL + (size_t)xc*PADA + (size_t)yc*PADV + zc;
  float acc[NCO];
  #pragma unroll
  for(int c=0;c<NCO;++c) acc[c]=0.f;
  for(int ci=0; ci<CIN; ++ci){
    const float* xch = xb + (size_t)ci*PADVOL;
    const float* Kc = Kf + ((size_t)co0*CIN + ci)*TAPS;
    #pragma unroll 1
    for(int dx=0; dx<7; ++dx){
      #pragma unroll 1
      for(int dy=0; dy<7; ++dy){
        const float* xr = xch + dx*PADA + dy*PADV;
        float xv[7];
        #pragma unroll
        for(int dz=0; dz<7; ++dz) xv[dz] = xr[dz];
        const float* Kr = Kc + dx*49 + dy*7;
        #pragma unroll
        for(int c=0;c<NCO;++c){
          const float* Krc = Kr + (size_t)c*CIN*TAPS;
          #pragma unroll
          for(int dz=0;dz<7;++dz)
            acc[c] = fmaf(xv[dz], Krc[dz], acc[c]);
        }
      }
    }
  }
  #pragma unroll
  for(int c=0;c<NCO;++c)
    y[((size_t)b*COUT + co0 + c)*PVOL + p] = acc[c];
}

// ---------------- kernel 6: bn stats ----------------
__global__ __launch_bounds__(256) void bn_stats_kernel(const float* __restrict__ y,
    const float* __restrict__ gamma, float* __restrict__ stats){
  int g = blockIdx.x, tid = threadIdx.x;
  int ch0, nc;
  if(g<8){ ch0=g; nc=1; }
  else if(g<16){ ch0=8+(g-8)*3; nc=3; }
  else { ch0=32+(g-16)*5; nc=5; }
  float s=0.f;
  for(int idx=tid; idx<2*PVOL; idx+=256){
    int b=idx/PVOL, p=idx%PVOL;
    const float* yb = y + ((size_t)b*COUT + ch0)*PVOL + p;
    for(int c=0;c<nc;++c){ float v = yb[(size_t)c*PVOL]; s += v*v; }
  }
  __shared__ float red[256];
  red[tid]=s; __syncthreads();
  for(int st=128; st>0; st>>=1){ if(tid<st) red[tid]+=red[tid+st]; __syncthreads(); }
  if(tid==0) stats[g] = gamma[g]/sqrtf(red[0]/16000.0f + 1e-5f);
}

// ---------------- kernel 7: apply scale/bias/relu ----------------
__global__ __launch_bounds__(256) void apply_kernel(float* __restrict__ y,
    const float* __restrict__ stats, const float* __restrict__ bias){
  int id = blockIdx.x*256 + threadIdx.x;
  if(id >= 2*COUT*PVOL) return;
  int c = (id/PVOL)%COUT;
  float val = y[id];
  if(c<8){ val = fmaxf(val*stats[c] + bias[c], 0.f); }
  else if(c<32){ val *= stats[8+(c-8)/3]; }
  else { val *= stats[16+(c-32)/5]; }
  y[id] = val;
}

// ---------------- launch ----------------
extern "C" void kernel_launch(void* const* d_in, const int* in_sizes, int n_in,
                              void* d_out, int out_size, void* d_ws, size_t ws_size,
                              hipStream_t stream){
  const float* x = (const float*)d_in[0];
  WPtrs W;
  for(int k=0;k<9;++k) W.p[k] = (const float*)d_in[1+k];
  const float* gamma = (const float*)d_in[10];
  const float* bias  = (const float*)d_in[11];
  float* ws = (float*)d_ws;
  float* consts = ws;
  float* xp = ws + OFF_XP;
  float* Kf = ws + OFF_K;
  float* stats = ws + OFF_STATS;
  float* y = (float*)d_out;

  hipMemsetAsync(xp, 0, XP_FLOATS*sizeof(float), stream);
  gen_cg_kernel<<<23,256,0,stream>>>(consts);
  gen_basis_kernel<<<57,256,0,stream>>>(consts);
  build_xin_kernel<<<(2*MCH*PVOL+255)/256,256,0,stream>>>(x, consts, xp);
  build_K_kernel<<<(int)((K_FLOATS+255)/256),256,0,stream>>>(W, consts, Kf);
  conv_kernel<<<dim3(32,COUT/NCO,2),256,0,stream>>>(xp, Kf, y);
  bn_stats_kernel<<<24,256,0,stream>>>(y, gamma, stats);
  apply_kernel<<<(2*COUT*PVOL+255)/256,256,0,stream>>>(y, stats, bias);
}

// Round 3
// 376.731 us; speedup vs baseline: 7.6347x; 7.6347x over previous
//
#include <hip/hip_runtime.h>
#include <hip/hip_bf16.h>
#include <cmath>

typedef unsigned short u16;
typedef __attribute__((ext_vector_type(4))) float f32x4;
typedef __attribute__((ext_vector_type(8))) short bf16x8;

// ---------------- problem constants ----------------
#define PVOL   8000
#define CIN    144
#define COUT   72
#define MCH    8

// ---------------- consts (fp32) float-offset layout ----------------
#define OFF_CG    81
#define OFF_Y     1306
#define OFF_RAD   9881
#define OFF_BASIS 10910
#define CONST_BYTES 1110016    // 277504 floats reserved

// XB: [b2][xi26][half2][yi26][zi26][c96] bf16 (zero-padded borders + ch pad)
#define XB_SLICE  64896        // ushorts per (b,xi,half) = 26*26*96
#define XB_BYTES  13498368
// KB: [tap343][half2][ks3][co80][kk32] bf16
#define KB_ELEMS  5268480
#define KB_BYTES  10536960

#define OFF_XB_BYTES   CONST_BYTES
#define OFF_KB_BYTES   (OFF_XB_BYTES + XB_BYTES)
#define OFF_STATS_BYTES (OFF_KB_BYTES + KB_BYTES)

// 19 basis-CG tasks (pair order (lo,li) = 00,01,02,10,11,12,20,21,22)
static __device__ const int T_LO[19]   = {0,0,0,1, 1,1,1, 1,1,1, 2, 2,2,2, 2,2,2,2,2};
static __device__ const int T_LI[19]   = {0,1,2,0, 1,1,1, 2,2,2, 0, 1,1,1, 2,2,2,2,2};
static __device__ const int T_L [19]   = {0,1,2,1, 0,1,2, 1,2,3, 2, 1,2,3, 0,1,2,3,4};
static __device__ const int T_CGOFF[19]= {0,1,10,35, 44,53,80, 125,170,245, 350, 375,420,495, 600,625,700,825,1000};
static __device__ const int PAIR_BOFF[9] = {0,1029,4116,9261,12348,40131,86436,91581,137886};

struct WPtrs { const float* p[9]; };

static __device__ inline u16 f2bf(float v){
  __hip_bfloat16 h = __float2bfloat16(v);
  return __builtin_bit_cast(u16, h);
}

// ---------------- device helpers (fp64) ----------------
__device__ inline double d_fact(int n){ double r=1.0; for(int i=2;i<=n;++i) r*=(double)i; return r; }

__device__ double d_su2cg(int j1,int j2,int j3,int m1,int m2,int m3){
  if(m1+m2!=m3) return 0.0;
  if(j3 < abs(j1-j2) || j3 > j1+j2) return 0.0;
  double pref = sqrt((2.0*j3+1.0)*d_fact(j3+j1-j2)*d_fact(j3-j1+j2)*d_fact(j1+j2-j3)/d_fact(j1+j2+j3+1));
  pref *= sqrt(d_fact(j3+m3)*d_fact(j3-m3)*d_fact(j1-m1)*d_fact(j1+m1)*d_fact(j2-m2)*d_fact(j2+m2));
  double s=0.0;
  for(int k=0;k<=j1+j2+j3;++k){
    int d1=j1+j2-j3-k, d2=j1-m1-k, d3=j2+m2-k, d4=j3-j2+m1+k, d5=j3-j1-m2+k;
    if(d1>=0&&d2>=0&&d3>=0&&d4>=0&&d5>=0)
      s += ((k&1)?-1.0:1.0)/(d_fact(k)*d_fact(d1)*d_fact(d2)*d_fact(d3)*d_fact(d4)*d_fact(d5));
  }
  return pref*s;
}

__device__ inline int d_urow(int l, int r, int* col, double* ure, double* uim){
  const double is2 = 0.7071067811865476;
  if(r==l){ col[0]=l; ure[0]=1.0; uim[0]=0.0; return 1; }
  if(r>l){ int m=r-l; double sg=(m&1)?-1.0:1.0;
    col[0]=l+m; ure[0]=sg*is2; uim[0]=0.0;
    col[1]=l-m; ure[1]=is2;    uim[1]=0.0; return 2; }
  int m=l-r;
  col[0]=l-m; ure[0]=0.0; uim[0]=is2;
  col[1]=l+m; ure[1]=0.0; uim[1]=-(((m&1)?-1.0:1.0))*is2;
  return 2;
}

__device__ void d_sph(double gx,double gy,double gz,double Y[25]){
  const double PI_ = 3.14159265358979323846;
  double r = sqrt(gx*gx+gy*gy+gz*gz);
  const double eps=1e-9;
  double ct = (r>eps)? gz/fmax(r,eps) : 1.0;
  double phi = atan2(gy,gx);
  double st2 = 1.0-ct*ct; if(st2<0.0) st2=0.0;
  double st = sqrt(st2);
  double P[5][5];
  P[0][0]=1.0;
  for(int m=1;m<=4;++m){
    double dfac=1.0; for(int k=1;k<2*m;k+=2) dfac*=(double)k;
    double stm=1.0; for(int k=0;k<m;++k) stm*=st;
    P[m][m] = ((m&1)?-1.0:1.0)*dfac*stm;
  }
  for(int m=0;m<4;++m) P[m+1][m] = ct*(2*m+1)*P[m][m];
  for(int m=0;m<=4;++m)
    for(int l=m+2;l<=4;++l)
      P[l][m] = ((2*l-1)*ct*P[l-1][m] - (l+m-1)*P[l-2][m])/(double)(l-m);
  int idx=0;
  for(int l=0;l<=4;++l){
    double arr[9];
    for(int k=0;k<2*l+1;++k) arr[k]=0.0;
    for(int m=0;m<=l;++m){
      double N = sqrt((2.0*l+1.0)/(4.0*PI_)*d_fact(l-m)/d_fact(l+m));
      if(m==0) arr[l] = N*P[l][0];
      else{
        arr[l+m]=sqrt(2.0)*N*P[l][m]*cos(m*phi);
        arr[l-m]=sqrt(2.0)*N*P[l][m]*sin(m*phi);
      }
    }
    if(l>0 && !(r>eps)) for(int k=0;k<2*l+1;++k) arr[k]=0.0;
    for(int k=0;k<2*l+1;++k) Y[idx++]=arr[k];
  }
}

// ---------------- kernel 1: CG tables + TPC + Y + RAD ----------------
__global__ __launch_bounds__(256) void gen_cg_kernel(float* __restrict__ consts){
  int task = blockIdx.x, tid = threadIdx.x;
  if(task==22){
    for(int t=tid; t<343; t+=256){
      int ix=t/49, iy=(t/7)%7, iz=t%7;
      double gx=ix-3, gy=iy-3, gz=iz-3;
      double Y[25]; d_sph(gx,gy,gz,Y);
      for(int k=0;k<25;++k) consts[OFF_Y + k*343 + t] = (float)Y[k];
      double r = sqrt(gx*gx+gy*gy+gz*gz);
      for(int j=0;j<3;++j){
        double d = r - 1.5*j;
        consts[OFF_RAD + j*343 + t] = (r<=3.5)? (float)exp(-0.5*d*d) : 0.0f;
      }
    }
    return;
  }
  int j1,j2,j3,outOff;
  if(task<19){ j1=T_LI[task]; j2=T_L[task]; j3=T_LO[task]; outOff = OFF_CG + T_CGOFF[task]; }
  else { int l=task-19; j1=1; j2=1; j3=l; outOff = (l==0)?0:((l==1)?9:36); }
  int n1=2*j1+1, n2=2*j2+1, n3=2*j3+1;
  int cnt = n1*n2*n3;  // <=225
  __shared__ double Cc[225];
  for(int e=tid; e<cnt; e+=256){
    int m=e/(n2*n3), n=(e/n3)%n2, c=e%n3;
    Cc[e] = d_su2cg(j1,j2,j3, m-j1, n-j2, c-j3);
  }
  __syncthreads();
  double tre=0.0, tim=0.0;
  int e = tid;
  if(e<cnt){
    int a=e/(n1*n2), i=(e/n2)%n1, jj=e%n2;
    int c3[2]; double r3[2], q3[2]; int nc3=d_urow(j3,a,c3,r3,q3);
    int c1[2]; double r1[2], q1[2]; int nc1=d_urow(j1,i,c1,r1,q1);
    int c2[2]; double r2[2], q2[2]; int nc2=d_urow(j2,jj,c2,r2,q2);
    for(int ic=0; ic<nc3; ++ic)
      for(int im=0; im<nc1; ++im)
        for(int in_=0; in_<nc2; ++in_){
          double cc = Cc[(c1[im]*n2 + c2[in_])*n3 + c3[ic]];
          if(cc==0.0) continue;
          double ar=r3[ic], ai=q3[ic];
          double br=r1[im], bi=-q1[im];
          double cr=r2[in_], cim=-q2[in_];
          double abr = ar*br - ai*bi, abi = ar*bi + ai*br;
          double zr = abr*cr - abi*cim, zi = abr*cim + abi*cr;
          tre += zr*cc; tim += zi*cc;
        }
  }
  __shared__ double mre[256], mim[256];
  mre[tid]=fabs(tre); mim[tid]=fabs(tim);
  __syncthreads();
  for(int s=128;s>0;s>>=1){ if(tid<s){ mre[tid]=fmax(mre[tid],mre[tid+s]); mim[tid]=fmax(mim[tid],mim[tid+s]); } __syncthreads(); }
  bool useim = mim[0] > mre[0];
  if(e<cnt) consts[outOff + e] = (float)(useim? tim : tre);
}

// ---------------- kernel 2: basis assembly + norm ----------------
__global__ __launch_bounds__(256) void gen_basis_kernel(float* __restrict__ consts){
  int task = blockIdx.x/3, j = blockIdx.x%3, tid=threadIdx.x;
  int lo=T_LO[task], li=T_LI[task], l=T_L[task];
  int A=2*lo+1, I=2*li+1, n2=2*l+1;
  int l_idx = l - abs(lo-li);
  const float* T = consts + OFF_CG + T_CGOFF[task];
  const float* Yl = consts + OFF_Y + l*l*343;
  const float* Rj = consts + OFF_RAD + j*343;
  float* out = consts + OFF_BASIS + PAIR_BOFF[lo*3+li] + (size_t)((l_idx*3 + j)*A*I)*343;
  int N = A*I*343;
  double ssq = 0.0;
  for(int e=tid; e<N; e+=256){
    int ai = e/343, t = e%343;
    double ang = 0.0;
    for(int m=0;m<n2;++m) ang += (double)T[ai*n2+m] * (double)Yl[m*343+t];
    double val = ang * (double)Rj[t];
    out[e] = (float)val;
    ssq += val*val;
  }
  __shared__ double red[256];
  red[tid]=ssq; __syncthreads();
  for(int s=128;s>0;s>>=1){ if(tid<s) red[tid]+=red[tid+s]; __syncthreads(); }
  double nrm = sqrt(red[0]);
  float scale = (nrm>1e-12)? (float)(1.0/nrm) : 1.0f;
  for(int e=tid; e<N; e+=256) out[e] *= scale;
}

// ---------------- kernel 3: build padded bf16 xin (fragment-native layout) ----------------
__global__ __launch_bounds__(256) void build_xin_kernel(const float* __restrict__ x,
    const float* __restrict__ consts, u16* __restrict__ XB){
  int id = blockIdx.x*256 + threadIdx.x;
  if(id >= 2*MCH*PVOL) return;
  int p = id % PVOL; int u = (id/PVOL)%MCH; int b = id/(MCH*PVOL);
  int xi=p/400, rr=p%400, yi=rr/20, zi=rr%20;
  const float* xb = x + (size_t)b*COUT*PVOL + p;
  float s  = xb[(size_t)u*PVOL];
  float vv[3], qq[5];
  for(int i=0;i<3;++i) vv[i] = xb[(size_t)(8+u*3+i)*PVOL];
  for(int i=0;i<5;++i) qq[i] = xb[(size_t)(32+u*5+i)*PVOL];
  const float* T0 = consts + 0;
  const float* T1 = consts + 9;
  const float* T2 = consts + 36;
  float i0=0.f, i1[3]={0,0,0}, i2[5]={0,0,0,0,0};
  for(int i=0;i<3;++i) for(int jj=0;jj<3;++jj){
    float vij = vv[i]*vv[jj];
    i0 += T0[i*3+jj]*vij;
    for(int a=0;a<3;++a) i1[a] += T1[(a*3+i)*3+jj]*vij;
    for(int a=0;a<5;++a) i2[a] += T2[(a*3+i)*3+jj]*vij;
  }
  size_t base_b = ((size_t)b*26 + (xi+3))*2;
  size_t pos = ((size_t)(yi+3))*26 + (zi+3);
  auto wr = [&](int ci, float v){
    int h = ci>=80 ? 1 : 0; int cl = ci - 80*h;
    XB[(base_b + h)*XB_SLICE + pos*96 + cl] = f2bf(v);
  };
  wr(u, s);
  wr(8+u, i0);
  for(int i=0;i<3;++i) wr(16+u*3+i, vv[i]);
  for(int a=0;a<3;++a) wr(40+u*3+a, i1[a]);
  for(int i=0;i<5;++i) wr(64+u*5+i, qq[i]);
  for(int a=0;a<5;++a) wr(104+u*5+a, i2[a]);
}

// ---------------- kernel 4: build K in bf16 MFMA layout ----------------
// KB[tap][half][ks][co80][kk32]
__global__ __launch_bounds__(256) void build_K_kernel(WPtrs W,
    const float* __restrict__ consts, u16* __restrict__ KB){
  size_t idx = (size_t)blockIdx.x*256 + threadIdx.x;
  if(idx >= KB_ELEMS) return;
  int kk = (int)(idx & 31);
  int co = (int)((idx>>5)%80);
  int ks = (int)((idx/2560)%3);
  int half = (int)((idx/7680)&1);
  int tap = (int)(idx/15360);
  int ci_l = ks*32 + kk;
  float acc = 0.f;
  bool valid = (co<72) && (half==0 ? (ci_l<80) : (ci_l<64));
  if(valid){
    int ci = half*80 + ci_l;
    int lo,u,a;
    if(co<8){ lo=0; u=co; a=0; }
    else if(co<32){ lo=1; u=(co-8)/3; a=(co-8)%3; }
    else { lo=2; u=(co-32)/5; a=(co-32)%5; }
    int li,vv,i;
    if(ci<16){ li=0; vv=ci; i=0; }
    else if(ci<64){ li=1; vv=(ci-16)/3; i=(ci-16)%3; }
    else { li=2; vv=(ci-64)/5; i=(ci-64)%5; }
    int pair = lo*3+li;
    int nl = 2*min(lo,li)+1;
    int A = 2*lo+1, I = 2*li+1;
    const float* bp = consts + OFF_BASIS + PAIR_BOFF[pair];
    const float* wp = W.p[pair];
    for(int lk=0; lk<nl; ++lk)
      for(int j=0;j<3;++j)
        acc = fmaf(wp[((u*16+vv)*nl+lk)*3+j],
                   bp[(size_t)(((lk*3+j)*A + a)*I + i)*343 + tap], acc);
  }
  KB[idx] = f2bf(acc);
}

// ---------------- kernel 5: MFMA implicit-GEMM conv (split-K over dx, atomic combine) ----------------
#define RS 104   // LDS row stride (ushorts)
__global__ __launch_bounds__(512) void conv_mfma(const u16* __restrict__ XB,
    const u16* __restrict__ KB, float* __restrict__ y){
  __shared__ __align__(16) u16 Bl[676*RS];   // 140,608 B
  int xo = blockIdx.x, dx = blockIdx.y, b = blockIdx.z;
  int tid = threadIdx.x;
  int w = tid>>6, l = tid&63, lrow = l&15, lseg = l>>4;
  int nf0 = (w<7)? w*3 : 21;
  int NF  = (w<7)? 3 : 4;
  f32x4 acc[5][4];
  #pragma unroll
  for(int mf=0;mf<5;++mf)
    #pragma unroll
    for(int f=0;f<4;++f) acc[mf][f] = (f32x4){0.f,0.f,0.f,0.f};
  int row0[4];
  #pragma unroll
  for(int f=0;f<4;++f){ int n=(nf0+f)*16+lrow; row0[f]=(n/20)*26 + (n%20); }

  for(int half=0; half<2; ++half){
    __syncthreads();
    const u16* src = XB + ((size_t)(b*26 + xo + dx)*2 + half)*XB_SLICE;
    for(int c=tid; c<8112; c+=512){
      ulonglong2 v = ((const ulonglong2*)src)[c];
      int row = c/12, wi = c - row*12;
      *(ulonglong2*)(Bl + row*RS + wi*8) = v;
    }
    __syncthreads();
    for(int dy=0; dy<7; ++dy){
      int rem = 12 - (dx-3)*(dx-3) - (dy-3)*(dy-3);
      if(rem < 0) continue;
      int s3 = (rem>=9)?3:((rem>=4)?2:((rem>=1)?1:0));
      for(int dz=3-s3; dz<=3+s3; ++dz){
        const u16* ka = KB + (size_t)((dx*49+dy*7+dz)*2 + half)*7680;
        int rb = dy*26 + dz;
        #pragma unroll
        for(int ks=0; ks<3; ++ks){
          bf16x8 af[5];
          #pragma unroll
          for(int mf=0;mf<5;++mf)
            af[mf] = *(const bf16x8*)(ka + ks*2560 + (mf*16+lrow)*32 + lseg*8);
          #pragma unroll
          for(int f=0; f<4; ++f){
            if(f < NF){
              bf16x8 bv = *(const bf16x8*)(Bl + (row0[f]+rb)*RS + ks*32 + lseg*8);
              #pragma unroll
              for(int mf=0;mf<5;++mf)
                acc[mf][f] = __builtin_amdgcn_mfma_f32_16x16x32_bf16(af[mf], bv, acc[mf][f], 0, 0, 0);
            }
          }
        }
      }
    }
  }
  // epilogue: atomic combine across the 7 dx blocks. C/D: col=lane&15 (n), row=(lane>>4)*4+r (co)
  #pragma unroll
  for(int f=0; f<4; ++f){
    if(f < NF){
      int n = (nf0+f)*16 + lrow;
      #pragma unroll
      for(int mf=0; mf<5; ++mf){
        #pragma unroll
        for(int r=0; r<4; ++r){
          int co = mf*16 + lseg*4 + r;
          if(co < 72)
            atomicAdd(&y[((size_t)(b*COUT+co)*20 + xo)*400 + n], acc[mf][f][r]);
        }
      }
    }
  }
}

// ---------------- kernel 6: bn stats ----------------
__global__ __launch_bounds__(256) void bn_stats_kernel(const float* __restrict__ y,
    const float* __restrict__ gamma, float* __restrict__ stats){
  int g = blockIdx.x, tid = threadIdx.x;
  int ch0, nc;
  if(g<8){ ch0=g; nc=1; }
  else if(g<16){ ch0=8+(g-8)*3; nc=3; }
  else { ch0=32+(g-16)*5; nc=5; }
  float s=0.f;
  for(int idx=tid; idx<2*PVOL; idx+=256){
    int b=idx/PVOL, p=idx%PVOL;
    const float* yb = y + ((size_t)b*COUT + ch0)*PVOL + p;
    for(int c=0;c<nc;++c){ float v = yb[(size_t)c*PVOL]; s += v*v; }
  }
  __shared__ float red[256];
  red[tid]=s; __syncthreads();
  for(int st=128; st>0; st>>=1){ if(tid<st) red[tid]+=red[tid+st]; __syncthreads(); }
  if(tid==0) stats[g] = gamma[g]/sqrtf(red[0]/16000.0f + 1e-5f);
}

// ---------------- kernel 7: apply scale/bias/relu ----------------
__global__ __launch_bounds__(256) void apply_kernel(float* __restrict__ y,
    const float* __restrict__ stats, const float* __restrict__ bias){
  int id = blockIdx.x*256 + threadIdx.x;
  if(id >= 2*COUT*PVOL) return;
  int c = (id/PVOL)%COUT;
  float val = y[id];
  if(c<8){ val = fmaxf(val*stats[c] + bias[c], 0.f); }
  else if(c<32){ val *= stats[8+(c-8)/3]; }
  else { val *= stats[16+(c-32)/5]; }
  y[id] = val;
}

// ---------------- launch ----------------
extern "C" void kernel_launch(void* const* d_in, const int* in_sizes, int n_in,
                              void* d_out, int out_size, void* d_ws, size_t ws_size,
                              hipStream_t stream){
  const float* x = (const float*)d_in[0];
  WPtrs W;
  for(int k=0;k<9;++k) W.p[k] = (const float*)d_in[1+k];
  const float* gamma = (const float*)d_in[10];
  const float* bias  = (const float*)d_in[11];
  char* base = (char*)d_ws;
  float* consts = (float*)base;
  u16* XB = (u16*)(base + OFF_XB_BYTES);
  u16* KB = (u16*)(base + OFF_KB_BYTES);
  float* stats = (float*)(base + OFF_STATS_BYTES);
  float* y = (float*)d_out;

  hipMemsetAsync(XB, 0, XB_BYTES, stream);
  hipMemsetAsync(y, 0, (size_t)2*COUT*PVOL*sizeof(float), stream);
  gen_cg_kernel<<<23,256,0,stream>>>(consts);
  gen_basis_kernel<<<57,256,0,stream>>>(consts);
  build_xin_kernel<<<(2*MCH*PVOL+255)/256,256,0,stream>>>(x, consts, XB);
  build_K_kernel<<<(KB_ELEMS+255)/256,256,0,stream>>>(W, consts, KB);
  conv_mfma<<<dim3(20,7,2),512,0,stream>>>(XB, KB, y);
  bn_stats_kernel<<<24,256,0,stream>>>(y, gamma, stats);
  apply_kernel<<<(2*COUT*PVOL+255)/256,256,0,stream>>>(y, stats, bias);
}

// Round 4
// 280.498 us; speedup vs baseline: 10.2540x; 1.3431x over previous
//
#include <hip/hip_runtime.h>
#include <hip/hip_bf16.h>
#include <cmath>

typedef unsigned short u16;
typedef __attribute__((ext_vector_type(4))) float f32x4;
typedef __attribute__((ext_vector_type(8))) short bf16x8;

// ---------------- problem constants ----------------
#define PVOL   8000
#define CIN    144
#define COUT   72
#define MCH    8

// ---------------- consts (fp32) float-offset layout ----------------
#define OFF_CG    81
#define OFF_Y     1306
#define OFF_RAD   9881
#define OFF_BASIS 10910
#define CONST_BYTES 1110016    // 277504 floats reserved

// XB: [b2][xi26][half2][yi26][zi26][c96] bf16 (zero-padded borders + ch pad)
#define XB_SLICE  64896        // ushorts per (b,xi,half) = 26*26*96
#define XB_BYTES  13498368
// KB: [tap343][half2][ks3][co80][kk32] bf16
#define KB_ELEMS  5268480
#define KB_BYTES  10536960

#define OFF_XB_BYTES   CONST_BYTES
#define OFF_KB_BYTES   (OFF_XB_BYTES + XB_BYTES)
#define OFF_STATS_BYTES (OFF_KB_BYTES + KB_BYTES)

// 19 basis-CG tasks (pair order (lo,li) = 00,01,02,10,11,12,20,21,22)
static __device__ const int T_LO[19]   = {0,0,0,1, 1,1,1, 1,1,1, 2, 2,2,2, 2,2,2,2,2};
static __device__ const int T_LI[19]   = {0,1,2,0, 1,1,1, 2,2,2, 0, 1,1,1, 2,2,2,2,2};
static __device__ const int T_L [19]   = {0,1,2,1, 0,1,2, 1,2,3, 2, 1,2,3, 0,1,2,3,4};
static __device__ const int T_CGOFF[19]= {0,1,10,35, 44,53,80, 125,170,245, 350, 375,420,495, 600,625,700,825,1000};
static __device__ const int PAIR_BOFF[9] = {0,1029,4116,9261,12348,40131,86436,91581,137886};
// build_K LDS staging tables
static __device__ const int NL_P[9]   = {1,1,1,1,3,3,1,3,5};
static __device__ const int WSOFF[9]  = {0,384,768,1152,1536,2688,3840,4224,5376};   // 384*nl cumsum (7296 total)
static __device__ const int BSOFF[9]  = {0,3,12,27,36,117,252,267,402};              // PAIR_BOFF/343 (777 total)

// tap tables: (dy<<4)|dz for the r^2<=12 ball, per |dx-3| class
static __device__ const unsigned char TAP_S[9] = {   // dx in {0,6}
  0x22,0x23,0x24, 0x32,0x33,0x34, 0x42,0x43,0x44};
static __device__ const unsigned char TAP_M[25] = {  // dx in {1,5}
  0x11,0x12,0x13,0x14,0x15, 0x21,0x22,0x23,0x24,0x25,
  0x31,0x32,0x33,0x34,0x35, 0x41,0x42,0x43,0x44,0x45,
  0x51,0x52,0x53,0x54,0x55};
static __device__ const unsigned char TAP_B[37] = {  // dx in {2,3,4}
  0x02,0x03,0x04,
  0x11,0x12,0x13,0x14,0x15,
  0x20,0x21,0x22,0x23,0x24,0x25,0x26,
  0x30,0x31,0x32,0x33,0x34,0x35,0x36,
  0x40,0x41,0x42,0x43,0x44,0x45,0x46,
  0x51,0x52,0x53,0x54,0x55,
  0x62,0x63,0x64};

struct WPtrs { const float* p[9]; };

static __device__ inline u16 f2bf(float v){
  __hip_bfloat16 h = __float2bfloat16(v);
  return __builtin_bit_cast(u16, h);
}

// ---------------- device helpers (fp64) ----------------
__device__ inline double d_fact(int n){ double r=1.0; for(int i=2;i<=n;++i) r*=(double)i; return r; }

__device__ double d_su2cg(int j1,int j2,int j3,int m1,int m2,int m3){
  if(m1+m2!=m3) return 0.0;
  if(j3 < abs(j1-j2) || j3 > j1+j2) return 0.0;
  double pref = sqrt((2.0*j3+1.0)*d_fact(j3+j1-j2)*d_fact(j3-j1+j2)*d_fact(j1+j2-j3)/d_fact(j1+j2+j3+1));
  pref *= sqrt(d_fact(j3+m3)*d_fact(j3-m3)*d_fact(j1-m1)*d_fact(j1+m1)*d_fact(j2-m2)*d_fact(j2+m2));
  double s=0.0;
  for(int k=0;k<=j1+j2+j3;++k){
    int d1=j1+j2-j3-k, d2=j1-m1-k, d3=j2+m2-k, d4=j3-j2+m1+k, d5=j3-j1-m2+k;
    if(d1>=0&&d2>=0&&d3>=0&&d4>=0&&d5>=0)
      s += ((k&1)?-1.0:1.0)/(d_fact(k)*d_fact(d1)*d_fact(d2)*d_fact(d3)*d_fact(d4)*d_fact(d5));
  }
  return pref*s;
}

__device__ inline int d_urow(int l, int r, int* col, double* ure, double* uim){
  const double is2 = 0.7071067811865476;
  if(r==l){ col[0]=l; ure[0]=1.0; uim[0]=0.0; return 1; }
  if(r>l){ int m=r-l; double sg=(m&1)?-1.0:1.0;
    col[0]=l+m; ure[0]=sg*is2; uim[0]=0.0;
    col[1]=l-m; ure[1]=is2;    uim[1]=0.0; return 2; }
  int m=l-r;
  col[0]=l-m; ure[0]=0.0; uim[0]=is2;
  col[1]=l+m; ure[1]=0.0; uim[1]=-(((m&1)?-1.0:1.0))*is2;
  return 2;
}

__device__ void d_sph(double gx,double gy,double gz,double Y[25]){
  const double PI_ = 3.14159265358979323846;
  double r = sqrt(gx*gx+gy*gy+gz*gz);
  const double eps=1e-9;
  double ct = (r>eps)? gz/fmax(r,eps) : 1.0;
  double phi = atan2(gy,gx);
  double st2 = 1.0-ct*ct; if(st2<0.0) st2=0.0;
  double st = sqrt(st2);
  double P[5][5];
  P[0][0]=1.0;
  for(int m=1;m<=4;++m){
    double dfac=1.0; for(int k=1;k<2*m;k+=2) dfac*=(double)k;
    double stm=1.0; for(int k=0;k<m;++k) stm*=st;
    P[m][m] = ((m&1)?-1.0:1.0)*dfac*stm;
  }
  for(int m=0;m<4;++m) P[m+1][m] = ct*(2*m+1)*P[m][m];
  for(int m=0;m<=4;++m)
    for(int l=m+2;l<=4;++l)
      P[l][m] = ((2*l-1)*ct*P[l-1][m] - (l+m-1)*P[l-2][m])/(double)(l-m);
  int idx=0;
  for(int l=0;l<=4;++l){
    double arr[9];
    for(int k=0;k<2*l+1;++k) arr[k]=0.0;
    for(int m=0;m<=l;++m){
      double N = sqrt((2.0*l+1.0)/(4.0*PI_)*d_fact(l-m)/d_fact(l+m));
      if(m==0) arr[l] = N*P[l][0];
      else{
        arr[l+m]=sqrt(2.0)*N*P[l][m]*cos(m*phi);
        arr[l-m]=sqrt(2.0)*N*P[l][m]*sin(m*phi);
      }
    }
    if(l>0 && !(r>eps)) for(int k=0;k<2*l+1;++k) arr[k]=0.0;
    for(int k=0;k<2*l+1;++k) Y[idx++]=arr[k];
  }
}

// ---------------- kernel 1: CG tables + TPC + Y + RAD ----------------
__global__ __launch_bounds__(256) void gen_cg_kernel(float* __restrict__ consts){
  int task = blockIdx.x, tid = threadIdx.x;
  if(task==22){
    for(int t=tid; t<343; t+=256){
      int ix=t/49, iy=(t/7)%7, iz=t%7;
      double gx=ix-3, gy=iy-3, gz=iz-3;
      double Y[25]; d_sph(gx,gy,gz,Y);
      for(int k=0;k<25;++k) consts[OFF_Y + k*343 + t] = (float)Y[k];
      double r = sqrt(gx*gx+gy*gy+gz*gz);
      for(int j=0;j<3;++j){
        double d = r - 1.5*j;
        consts[OFF_RAD + j*343 + t] = (r<=3.5)? (float)exp(-0.5*d*d) : 0.0f;
      }
    }
    return;
  }
  int j1,j2,j3,outOff;
  if(task<19){ j1=T_LI[task]; j2=T_L[task]; j3=T_LO[task]; outOff = OFF_CG + T_CGOFF[task]; }
  else { int l=task-19; j1=1; j2=1; j3=l; outOff = (l==0)?0:((l==1)?9:36); }
  int n1=2*j1+1, n2=2*j2+1, n3=2*j3+1;
  int cnt = n1*n2*n3;  // <=225
  __shared__ double Cc[225];
  for(int e=tid; e<cnt; e+=256){
    int m=e/(n2*n3), n=(e/n3)%n2, c=e%n3;
    Cc[e] = d_su2cg(j1,j2,j3, m-j1, n-j2, c-j3);
  }
  __syncthreads();
  double tre=0.0, tim=0.0;
  int e = tid;
  if(e<cnt){
    int a=e/(n1*n2), i=(e/n2)%n1, jj=e%n2;
    int c3[2]; double r3[2], q3[2]; int nc3=d_urow(j3,a,c3,r3,q3);
    int c1[2]; double r1[2], q1[2]; int nc1=d_urow(j1,i,c1,r1,q1);
    int c2[2]; double r2[2], q2[2]; int nc2=d_urow(j2,jj,c2,r2,q2);
    for(int ic=0; ic<nc3; ++ic)
      for(int im=0; im<nc1; ++im)
        for(int in_=0; in_<nc2; ++in_){
          double cc = Cc[(c1[im]*n2 + c2[in_])*n3 + c3[ic]];
          if(cc==0.0) continue;
          double ar=r3[ic], ai=q3[ic];
          double br=r1[im], bi=-q1[im];
          double cr=r2[in_], cim=-q2[in_];
          double abr = ar*br - ai*bi, abi = ar*bi + ai*br;
          double zr = abr*cr - abi*cim, zi = abr*cim + abi*cr;
          tre += zr*cc; tim += zi*cc;
        }
  }
  __shared__ double mre[256], mim[256];
  mre[tid]=fabs(tre); mim[tid]=fabs(tim);
  __syncthreads();
  for(int s=128;s>0;s>>=1){ if(tid<s){ mre[tid]=fmax(mre[tid],mre[tid+s]); mim[tid]=fmax(mim[tid],mim[tid+s]); } __syncthreads(); }
  bool useim = mim[0] > mre[0];
  if(e<cnt) consts[outOff + e] = (float)(useim? tim : tre);
}

// ---------------- kernel 2: basis assembly + norm ----------------
__global__ __launch_bounds__(256) void gen_basis_kernel(float* __restrict__ consts){
  int task = blockIdx.x/3, j = blockIdx.x%3, tid=threadIdx.x;
  int lo=T_LO[task], li=T_LI[task], l=T_L[task];
  int A=2*lo+1, I=2*li+1, n2=2*l+1;
  int l_idx = l - abs(lo-li);
  const float* T = consts + OFF_CG + T_CGOFF[task];
  const float* Yl = consts + OFF_Y + l*l*343;
  const float* Rj = consts + OFF_RAD + j*343;
  float* out = consts + OFF_BASIS + PAIR_BOFF[lo*3+li] + (size_t)((l_idx*3 + j)*A*I)*343;
  int N = A*I*343;
  double ssq = 0.0;
  for(int e=tid; e<N; e+=256){
    int ai = e/343, t = e%343;
    double ang = 0.0;
    for(int m=0;m<n2;++m) ang += (double)T[ai*n2+m] * (double)Yl[m*343+t];
    double val = ang * (double)Rj[t];
    out[e] = (float)val;
    ssq += val*val;
  }
  __shared__ double red[256];
  red[tid]=ssq; __syncthreads();
  for(int s=128;s>0;s>>=1){ if(tid<s) red[tid]+=red[tid+s]; __syncthreads(); }
  double nrm = sqrt(red[0]);
  float scale = (nrm>1e-12)? (float)(1.0/nrm) : 1.0f;
  for(int e=tid; e<N; e+=256) out[e] *= scale;
}

// ---------------- kernel 3: build padded bf16 xin (fragment-native layout) ----------------
__global__ __launch_bounds__(256) void build_xin_kernel(const float* __restrict__ x,
    const float* __restrict__ consts, u16* __restrict__ XB){
  int id = blockIdx.x*256 + threadIdx.x;
  if(id >= 2*MCH*PVOL) return;
  int p = id % PVOL; int u = (id/PVOL)%MCH; int b = id/(MCH*PVOL);
  int xi=p/400, rr=p%400, yi=rr/20, zi=rr%20;
  const float* xb = x + (size_t)b*COUT*PVOL + p;
  float s  = xb[(size_t)u*PVOL];
  float vv[3], qq[5];
  for(int i=0;i<3;++i) vv[i] = xb[(size_t)(8+u*3+i)*PVOL];
  for(int i=0;i<5;++i) qq[i] = xb[(size_t)(32+u*5+i)*PVOL];
  const float* T0 = consts + 0;
  const float* T1 = consts + 9;
  const float* T2 = consts + 36;
  float i0=0.f, i1[3]={0,0,0}, i2[5]={0,0,0,0,0};
  for(int i=0;i<3;++i) for(int jj=0;jj<3;++jj){
    float vij = vv[i]*vv[jj];
    i0 += T0[i*3+jj]*vij;
    for(int a=0;a<3;++a) i1[a] += T1[(a*3+i)*3+jj]*vij;
    for(int a=0;a<5;++a) i2[a] += T2[(a*3+i)*3+jj]*vij;
  }
  size_t base_b = ((size_t)b*26 + (xi+3))*2;
  size_t pos = ((size_t)(yi+3))*26 + (zi+3);
  auto wr = [&](int ci, float v){
    int h = ci>=80 ? 1 : 0; int cl = ci - 80*h;
    XB[(base_b + h)*XB_SLICE + pos*96 + cl] = f2bf(v);
  };
  wr(u, s);
  wr(8+u, i0);
  for(int i=0;i<3;++i) wr(16+u*3+i, vv[i]);
  for(int a=0;a<3;++a) wr(40+u*3+a, i1[a]);
  for(int i=0;i<5;++i) wr(64+u*5+i, qq[i]);
  for(int a=0;a<5;++a) wr(104+u*5+a, i2[a]);
}

// ---------------- kernel 4: build K (one block per tap, LDS-staged w+basis) ----------------
// KB[tap][half][ks][co80][kk32]
__global__ __launch_bounds__(256) void build_K_kernel(WPtrs W,
    const float* __restrict__ consts, u16* __restrict__ KB){
  int tap = blockIdx.x, tid = threadIdx.x;
  __shared__ float ws[7296];
  __shared__ float bs[777];
  for(int p=0;p<9;++p){
    int n = 384*NL_P[p];
    const float* wp = W.p[p];
    for(int e=tid; e<n; e+=256) ws[WSOFF[p]+e] = wp[e];
  }
  for(int f=tid; f<777; f+=256) bs[f] = consts[OFF_BASIS + f*343 + tap];
  __syncthreads();
  for(int o=tid; o<15360; o+=256){
    int kk = o&31;
    int co = (o>>5)%80;
    int ks = (o/2560)%3;
    int half = o/7680;
    int ci_l = ks*32 + kk;
    float acc = 0.f;
    bool valid = (co<72) && (half==0 ? (ci_l<80) : (ci_l<64));
    if(valid){
      int ci = half*80 + ci_l;
      int lo,u,a;
      if(co<8){ lo=0; u=co; a=0; }
      else if(co<32){ lo=1; u=(co-8)/3; a=(co-8)%3; }
      else { lo=2; u=(co-32)/5; a=(co-32)%5; }
      int li,vv,i;
      if(ci<16){ li=0; vv=ci; i=0; }
      else if(ci<64){ li=1; vv=(ci-16)/3; i=(ci-16)%3; }
      else { li=2; vv=(ci-64)/5; i=(ci-64)%5; }
      int p = lo*3+li;
      int nl = NL_P[p];
      int A = 2*lo+1, I = 2*li+1;
      const float* wb = ws + WSOFF[p] + (u*16+vv)*nl*3;
      const float* bb = bs + BSOFF[p];
      for(int lk=0; lk<nl; ++lk)
        for(int j=0;j<3;++j)
          acc = fmaf(wb[lk*3+j], bb[((lk*3+j)*A + a)*I + i], acc);
    }
    KB[(size_t)tap*15360 + o] = f2bf(acc);
  }
}

// ---------------- kernel 5: MFMA implicit-GEMM conv ----------------
// grid (20 xo, 6 dx-groups, 2 b) = 240 blocks, 512 threads (8 waves) — all co-resident.
// groups: g0 = {dx0, dx6} (9+9 taps), g1..g5 = {dx g} (25/37/37/37/25 taps)
#define RS 104   // LDS row stride (ushorts)
__global__ __launch_bounds__(512) void conv_mfma(const u16* __restrict__ XB,
    const u16* __restrict__ KB, float* __restrict__ y){
  __shared__ __align__(16) u16 Bl[676*RS];   // 140,608 B
  int xo = blockIdx.x, g = blockIdx.y, b = blockIdx.z;
  int tid = threadIdx.x;
  int w = tid>>6, l = tid&63, lrow = l&15, lseg = l>>4;
  int nf0 = (w<7)? w*3 : 21;
  int NF  = (w<7)? 3 : 4;
  f32x4 acc[5][4];
  #pragma unroll
  for(int mf=0;mf<5;++mf)
    #pragma unroll
    for(int f=0;f<4;++f) acc[mf][f] = (f32x4){0.f,0.f,0.f,0.f};
  int row0[4];
  #pragma unroll
  for(int f=0;f<4;++f){ int n=(nf0+f)*16+lrow; row0[f]=(n/20)*26 + (n%20); }

  int ndx = (g==0)? 2 : 1;
  for(int id=0; id<ndx; ++id){
    int dx = (g==0)? id*6 : g;
    const unsigned char* tl; int nt;
    if(dx==0 || dx==6){ tl = TAP_S; nt = 9; }
    else if(dx==1 || dx==5){ tl = TAP_M; nt = 25; }
    else { tl = TAP_B; nt = 37; }
    for(int half=0; half<2; ++half){
      __syncthreads();
      const u16* src = XB + ((size_t)(b*26 + xo + dx)*2 + half)*XB_SLICE;
      for(int c=tid; c<8112; c+=512){
        ulonglong2 v = ((const ulonglong2*)src)[c];
        int row = c/12, wi = c - row*12;
        *(ulonglong2*)(Bl + row*RS + wi*8) = v;
      }
      __syncthreads();
      auto kstep = [&](const u16* ka, int rb, int ks){
        bf16x8 af[5];
        #pragma unroll
        for(int mf=0;mf<5;++mf)
          af[mf] = *(const bf16x8*)(ka + ks*2560 + (mf*16+lrow)*32 + lseg*8);
        #pragma unroll
        for(int f=0; f<4; ++f){
          if(f < NF){
            bf16x8 bv = *(const bf16x8*)(Bl + (row0[f]+rb)*RS + ks*32 + lseg*8);
            #pragma unroll
            for(int mf=0;mf<5;++mf)
              acc[mf][f] = __builtin_amdgcn_mfma_f32_16x16x32_bf16(af[mf], bv, acc[mf][f], 0, 0, 0);
          }
        }
      };
      for(int t=0; t<nt; ++t){
        int code = tl[t];
        int dy = code>>4, dz = code&15;
        const u16* ka = KB + (size_t)((dx*49+dy*7+dz)*2 + half)*7680;
        int rb = dy*26 + dz;
        kstep(ka, rb, 0);
        kstep(ka, rb, 1);
        if(half==0) kstep(ka, rb, 2);   // half1 ks2 is all-zero padding: skip
      }
    }
  }
  // epilogue: atomic combine across the 6 dx-groups. C/D: col=lane&15 (n), row=(lane>>4)*4+r (co)
  #pragma unroll
  for(int f=0; f<4; ++f){
    if(f < NF){
      int n = (nf0+f)*16 + lrow;
      #pragma unroll
      for(int mf=0; mf<5; ++mf){
        #pragma unroll
        for(int r=0; r<4; ++r){
          int co = mf*16 + lseg*4 + r;
          if(co < 72)
            atomicAdd(&y[((size_t)(b*COUT+co)*20 + xo)*400 + n], acc[mf][f][r]);
        }
      }
    }
  }
}

// ---------------- kernel 6: bn partial sums (grid 24 x 16, atomic combine) ----------------
__global__ __launch_bounds__(256) void bn_partial_kernel(const float* __restrict__ y,
    float* __restrict__ stats){
  int g = blockIdx.x, chunk = blockIdx.y, tid = threadIdx.x;
  int ch0, nc;
  if(g<8){ ch0=g; nc=1; }
  else if(g<16){ ch0=8+(g-8)*3; nc=3; }
  else { ch0=32+(g-16)*5; nc=5; }
  float s=0.f;
  int lo = chunk*1000, hi = lo+1000;      // over 2*PVOL = 16000 positions
  for(int idx=lo+tid; idx<hi; idx+=256){
    int b = idx/PVOL, p = idx%PVOL;
    const float* yb = y + ((size_t)b*COUT + ch0)*PVOL + p;
    for(int c=0;c<nc;++c){ float v = yb[(size_t)c*PVOL]; s += v*v; }
  }
  __shared__ float red[256];
  red[tid]=s; __syncthreads();
  for(int st=128; st>0; st>>=1){ if(tid<st) red[tid]+=red[tid+st]; __syncthreads(); }
  if(tid==0) atomicAdd(&stats[g], red[0]);
}

// ---------------- kernel 7: apply scale/bias/relu ----------------
__global__ __launch_bounds__(256) void apply_kernel(float* __restrict__ y,
    const float* __restrict__ stats, const float* __restrict__ gamma,
    const float* __restrict__ bias){
  int id = blockIdx.x*256 + threadIdx.x;
  if(id >= 2*COUT*PVOL) return;
  int c = (id/PVOL)%COUT;
  int g = (c<8)? c : ((c<32)? 8+(c-8)/3 : 16+(c-32)/5);
  float scale = gamma[g]*rsqrtf(stats[g]*(1.f/16000.f) + 1e-5f);
  float val = y[id]*scale;
  if(c<8) val = fmaxf(val + bias[c], 0.f);
  y[id] = val;
}

// ---------------- launch ----------------
extern "C" void kernel_launch(void* const* d_in, const int* in_sizes, int n_in,
                              void* d_out, int out_size, void* d_ws, size_t ws_size,
                              hipStream_t stream){
  const float* x = (const float*)d_in[0];
  WPtrs W;
  for(int k=0;k<9;++k) W.p[k] = (const float*)d_in[1+k];
  const float* gamma = (const float*)d_in[10];
  const float* bias  = (const float*)d_in[11];
  char* base = (char*)d_ws;
  float* consts = (float*)base;
  u16* XB = (u16*)(base + OFF_XB_BYTES);
  u16* KB = (u16*)(base + OFF_KB_BYTES);
  float* stats = (float*)(base + OFF_STATS_BYTES);
  float* y = (float*)d_out;

  hipMemsetAsync(XB, 0, XB_BYTES, stream);
  hipMemsetAsync(y, 0, (size_t)2*COUT*PVOL*sizeof(float), stream);
  hipMemsetAsync(stats, 0, 24*sizeof(float), stream);
  gen_cg_kernel<<<23,256,0,stream>>>(consts);
  gen_basis_kernel<<<57,256,0,stream>>>(consts);
  build_xin_kernel<<<(2*MCH*PVOL+255)/256,256,0,stream>>>(x, consts, XB);
  build_K_kernel<<<343,256,0,stream>>>(W, consts, KB);
  conv_mfma<<<dim3(20,6,2),512,0,stream>>>(XB, KB, y);
  bn_partial_kernel<<<dim3(24,16),256,0,stream>>>(y, stats);
  apply_kernel<<<(2*COUT*PVOL+255)/256,256,0,stream>>>(y, stats, gamma, bias);
}

// Round 5
// 274.862 us; speedup vs baseline: 10.4643x; 1.0205x over previous
//
#include <hip/hip_runtime.h>
#include <hip/hip_bf16.h>
#include <cmath>

typedef unsigned short u16;
typedef __attribute__((ext_vector_type(4))) float f32x4;
typedef __attribute__((ext_vector_type(8))) short bf16x8;

// ---------------- problem constants ----------------
#define PVOL   8000
#define CIN    144
#define COUT   72
#define MCH    8

// ---------------- consts (fp32) float-offset layout ----------------
#define OFF_BASIS 10910
#define CONST_BYTES 1110016    // 277504 floats reserved

// XB: [b2][xi26][half2][yi26][zi26][c96] bf16 (zero-padded borders + ch pad)
#define XB_SLICE  64896        // ushorts per (b,xi,half) = 26*26*96
#define XB_BYTES  13498368
// KB: [tap343][half2][ks3][co80][kk32] bf16
#define KB_ELEMS  5268480
#define KB_BYTES  10536960

#define OFF_XB_BYTES   CONST_BYTES
#define OFF_KB_BYTES   (OFF_XB_BYTES + XB_BYTES)
#define OFF_STATS_BYTES (OFF_KB_BYTES + KB_BYTES)

// 19 basis-CG tasks (pair order (lo,li) = 00,01,02,10,11,12,20,21,22)
static __device__ const int T_LO[19]   = {0,0,0,1, 1,1,1, 1,1,1, 2, 2,2,2, 2,2,2,2,2};
static __device__ const int T_LI[19]   = {0,1,2,0, 1,1,1, 2,2,2, 0, 1,1,1, 2,2,2,2,2};
static __device__ const int T_L [19]   = {0,1,2,1, 0,1,2, 1,2,3, 2, 1,2,3, 0,1,2,3,4};
static __device__ const int PAIR_BOFF[9] = {0,1029,4116,9261,12348,40131,86436,91581,137886};
// build_K LDS staging tables
static __device__ const int NL_P[9]   = {1,1,1,1,3,3,1,3,5};
static __device__ const int WSOFF[9]  = {0,384,768,1152,1536,2688,3840,4224,5376};   // 384*nl cumsum (7296 total)
static __device__ const int BSOFF[9]  = {0,3,12,27,36,117,252,267,402};              // PAIR_BOFF/343 (777 total)

// tap tables: (dy<<4)|dz for the r^2<=12 ball, per |dx-3| class
static __device__ const unsigned char TAP_S[9] = {   // dx in {0,6}
  0x22,0x23,0x24, 0x32,0x33,0x34, 0x42,0x43,0x44};
static __device__ const unsigned char TAP_M[25] = {  // dx in {1,5}
  0x11,0x12,0x13,0x14,0x15, 0x21,0x22,0x23,0x24,0x25,
  0x31,0x32,0x33,0x34,0x35, 0x41,0x42,0x43,0x44,0x45,
  0x51,0x52,0x53,0x54,0x55};
static __device__ const unsigned char TAP_B[37] = {  // dx in {2,3,4}
  0x02,0x03,0x04,
  0x11,0x12,0x13,0x14,0x15,
  0x20,0x21,0x22,0x23,0x24,0x25,0x26,
  0x30,0x31,0x32,0x33,0x34,0x35,0x36,
  0x40,0x41,0x42,0x43,0x44,0x45,0x46,
  0x51,0x52,0x53,0x54,0x55,
  0x62,0x63,0x64};

struct WPtrs { const float* p[9]; };

static __device__ inline u16 f2bf(float v){
  __hip_bfloat16 h = __float2bfloat16(v);
  return __builtin_bit_cast(u16, h);
}

// ---------------- device helpers (fp64) ----------------
__device__ inline double d_fact(int n){ double r=1.0; for(int i=2;i<=n;++i) r*=(double)i; return r; }

__device__ double d_su2cg(int j1,int j2,int j3,int m1,int m2,int m3){
  if(m1+m2!=m3) return 0.0;
  if(j3 < abs(j1-j2) || j3 > j1+j2) return 0.0;
  double pref = sqrt((2.0*j3+1.0)*d_fact(j3+j1-j2)*d_fact(j3-j1+j2)*d_fact(j1+j2-j3)/d_fact(j1+j2+j3+1));
  pref *= sqrt(d_fact(j3+m3)*d_fact(j3-m3)*d_fact(j1-m1)*d_fact(j1+m1)*d_fact(j2-m2)*d_fact(j2+m2));
  double s=0.0;
  for(int k=0;k<=j1+j2+j3;++k){
    int d1=j1+j2-j3-k, d2=j1-m1-k, d3=j2+m2-k, d4=j3-j2+m1+k, d5=j3-j1-m2+k;
    if(d1>=0&&d2>=0&&d3>=0&&d4>=0&&d5>=0)
      s += ((k&1)?-1.0:1.0)/(d_fact(k)*d_fact(d1)*d_fact(d2)*d_fact(d3)*d_fact(d4)*d_fact(d5));
  }
  return pref*s;
}

__device__ inline int d_urow(int l, int r, int* col, double* ure, double* uim){
  const double is2 = 0.7071067811865476;
  if(r==l){ col[0]=l; ure[0]=1.0; uim[0]=0.0; return 1; }
  if(r>l){ int m=r-l; double sg=(m&1)?-1.0:1.0;
    col[0]=l+m; ure[0]=sg*is2; uim[0]=0.0;
    col[1]=l-m; ure[1]=is2;    uim[1]=0.0; return 2; }
  int m=l-r;
  col[0]=l-m; ure[0]=0.0; uim[0]=is2;
  col[1]=l+m; ure[1]=0.0; uim[1]=-(((m&1)?-1.0:1.0))*is2;
  return 2;
}

__device__ void d_sph(double gx,double gy,double gz,double Y[25]){
  const double PI_ = 3.14159265358979323846;
  double r = sqrt(gx*gx+gy*gy+gz*gz);
  const double eps=1e-9;
  double ct = (r>eps)? gz/fmax(r,eps) : 1.0;
  double phi = atan2(gy,gx);
  double st2 = 1.0-ct*ct; if(st2<0.0) st2=0.0;
  double st = sqrt(st2);
  double P[5][5];
  P[0][0]=1.0;
  for(int m=1;m<=4;++m){
    double dfac=1.0; for(int k=1;k<2*m;k+=2) dfac*=(double)k;
    double stm=1.0; for(int k=0;k<m;++k) stm*=st;
    P[m][m] = ((m&1)?-1.0:1.0)*dfac*stm;
  }
  for(int m=0;m<4;++m) P[m+1][m] = ct*(2*m+1)*P[m][m];
  for(int m=0;m<=4;++m)
    for(int l=m+2;l<=4;++l)
      P[l][m] = ((2*l-1)*ct*P[l-1][m] - (l+m-1)*P[l-2][m])/(double)(l-m);
  int idx=0;
  for(int l=0;l<=4;++l){
    double arr[9];
    for(int k=0;k<2*l+1;++k) arr[k]=0.0;
    for(int m=0;m<=l;++m){
      double N = sqrt((2.0*l+1.0)/(4.0*PI_)*d_fact(l-m)/d_fact(l+m));
      if(m==0) arr[l] = N*P[l][0];
      else{
        arr[l+m]=sqrt(2.0)*N*P[l][m]*cos(m*phi);
        arr[l-m]=sqrt(2.0)*N*P[l][m]*sin(m*phi);
      }
    }
    if(l>0 && !(r>eps)) for(int k=0;k<2*l+1;++k) arr[k]=0.0;
    for(int k=0;k<2*l+1;++k) Y[idx++]=arr[k];
  }
}

// ---------------- kernel 1: fused CG + Y + RAD + basis (+ TPC) ----------------
// blocks 0..56: basis task (task = blk/3, radial j = blk%3). block 57: TPC.
__global__ __launch_bounds__(256) void gen_all_kernel(float* __restrict__ consts){
  __shared__ double Cc[225];
  __shared__ float  Tt[225];
  __shared__ float  Ylds[9*343];
  __shared__ float  Rlds[343];
  __shared__ double mre[256], mim[256];
  __shared__ double red[256];
  int tid = threadIdx.x;

  if(blockIdx.x == 57){
    // TPC tensors (j1=j2=1, j3=l), out offsets {0,9,36}
    for(int l=0;l<3;++l){
      int n1=3, n2=3, n3=2*l+1, cnt=n1*n2*n3;
      int outOff = (l==0)?0:((l==1)?9:36);
      __syncthreads();
      for(int e=tid;e<cnt;e+=256){
        int m=e/(n2*n3), n=(e/n3)%n2, c=e%n3;
        Cc[e]=d_su2cg(1,1,l, m-1, n-1, c-l);
      }
      __syncthreads();
      double tre=0.0, tim=0.0;
      int e=tid;
      if(e<cnt){
        int a=e/(n1*n2), i=(e/n2)%n1, jj=e%n2;
        int c3[2]; double r3[2], q3[2]; int nc3=d_urow(l,a,c3,r3,q3);
        int c1[2]; double r1[2], q1[2]; int nc1=d_urow(1,i,c1,r1,q1);
        int c2[2]; double r2[2], q2[2]; int nc2=d_urow(1,jj,c2,r2,q2);
        for(int ic=0; ic<nc3; ++ic)
          for(int im=0; im<nc1; ++im)
            for(int in_=0; in_<nc2; ++in_){
              double cc = Cc[(c1[im]*n2 + c2[in_])*n3 + c3[ic]];
              if(cc==0.0) continue;
              double ar=r3[ic], ai=q3[ic];
              double br=r1[im], bi=-q1[im];
              double cr=r2[in_], cim=-q2[in_];
              double abr = ar*br - ai*bi, abi = ar*bi + ai*br;
              double zr = abr*cr - abi*cim, zi = abr*cim + abi*cr;
              tre += zr*cc; tim += zi*cc;
            }
      }
      mre[tid]=fabs(tre); mim[tid]=fabs(tim);
      __syncthreads();
      for(int s=128;s>0;s>>=1){ if(tid<s){ mre[tid]=fmax(mre[tid],mre[tid+s]); mim[tid]=fmax(mim[tid],mim[tid+s]); } __syncthreads(); }
      bool useim = mim[0] > mre[0];
      if(e<cnt) consts[outOff + e] = (float)(useim? tim : tre);
      __syncthreads();
    }
    return;
  }

  int task = blockIdx.x/3, jrad = blockIdx.x%3;
  int lo=T_LO[task], li=T_LI[task], l=T_L[task];
  int j1=li, j2=l, j3=lo;
  int n1=2*j1+1, n2=2*j2+1, n3=2*j3+1, cnt=n1*n2*n3;
  // phase A: complex CG in LDS
  for(int e=tid;e<cnt;e+=256){
    int m=e/(n2*n3), n=(e/n3)%n2, c=e%n3;
    Cc[e]=d_su2cg(j1,j2,j3, m-j1, n-j2, c-j3);
  }
  __syncthreads();
  // phase B: real CG (U-transform + re/im vote) into Tt
  double tre=0.0, tim=0.0;
  int e=tid;
  if(e<cnt){
    int a=e/(n1*n2), i=(e/n2)%n1, jj=e%n2;
    int c3[2]; double r3[2], q3[2]; int nc3=d_urow(j3,a,c3,r3,q3);
    int c1[2]; double r1[2], q1[2]; int nc1=d_urow(j1,i,c1,r1,q1);
    int c2[2]; double r2[2], q2[2]; int nc2=d_urow(j2,jj,c2,r2,q2);
    for(int ic=0; ic<nc3; ++ic)
      for(int im=0; im<nc1; ++im)
        for(int in_=0; in_<nc2; ++in_){
          double cc = Cc[(c1[im]*n2 + c2[in_])*n3 + c3[ic]];
          if(cc==0.0) continue;
          double ar=r3[ic], ai=q3[ic];
          double br=r1[im], bi=-q1[im];
          double cr=r2[in_], cim=-q2[in_];
          double abr = ar*br - ai*bi, abi = ar*bi + ai*br;
          double zr = abr*cr - abi*cim, zi = abr*cim + abi*cr;
          tre += zr*cc; tim += zi*cc;
        }
  }
  mre[tid]=fabs(tre); mim[tid]=fabs(tim);
  __syncthreads();
  for(int s=128;s>0;s>>=1){ if(tid<s){ mre[tid]=fmax(mre[tid],mre[tid+s]); mim[tid]=fmax(mim[tid],mim[tid+s]); } __syncthreads(); }
  bool useim = mim[0] > mre[0];
  if(e<cnt) Tt[e] = (float)(useim? tim : tre);
  // phase C: Y rows for this l + radial row jrad
  for(int t=tid; t<343; t+=256){
    int ix=t/49, iy=(t/7)%7, iz=t%7;
    double gx=ix-3, gy=iy-3, gz=iz-3;
    double Y25[25]; d_sph(gx,gy,gz,Y25);
    for(int m=0;m<n2;++m) Ylds[m*343+t] = (float)Y25[l*l+m];
    double r = sqrt(gx*gx+gy*gy+gz*gz);
    double d = r - 1.5*jrad;
    Rlds[t] = (r<=3.5)? (float)exp(-0.5*d*d) : 0.0f;
  }
  __syncthreads();
  // phase D: basis = (Tt . Y) * RAD, then normalize
  int A=2*lo+1, I=2*li+1;
  int l_idx = l - abs(lo-li);
  float* out = consts + OFF_BASIS + PAIR_BOFF[lo*3+li] + (size_t)((l_idx*3 + jrad)*A*I)*343;
  int N = A*I*343;
  double ssq = 0.0;
  for(int ee=tid; ee<N; ee+=256){
    int ai = ee/343, t = ee%343;
    double ang = 0.0;
    for(int m=0;m<n2;++m) ang += (double)Tt[ai*n2+m] * (double)Ylds[m*343+t];
    double val = ang * (double)Rlds[t];
    out[ee] = (float)val;
    ssq += val*val;
  }
  red[tid]=ssq; __syncthreads();
  for(int s=128;s>0;s>>=1){ if(tid<s) red[tid]+=red[tid+s]; __syncthreads(); }
  double nrm = sqrt(red[0]);
  float scale = (nrm>1e-12)? (float)(1.0/nrm) : 1.0f;
  for(int ee=tid; ee<N; ee+=256) out[ee] *= scale;
}

// ---------------- kernel 3: build padded bf16 xin (fragment-native layout) ----------------
__global__ __launch_bounds__(256) void build_xin_kernel(const float* __restrict__ x,
    const float* __restrict__ consts, u16* __restrict__ XB){
  int id = blockIdx.x*256 + threadIdx.x;
  if(id >= 2*MCH*PVOL) return;
  int p = id % PVOL; int u = (id/PVOL)%MCH; int b = id/(MCH*PVOL);
  int xi=p/400, rr=p%400, yi=rr/20, zi=rr%20;
  const float* xb = x + (size_t)b*COUT*PVOL + p;
  float s  = xb[(size_t)u*PVOL];
  float vv[3], qq[5];
  for(int i=0;i<3;++i) vv[i] = xb[(size_t)(8+u*3+i)*PVOL];
  for(int i=0;i<5;++i) qq[i] = xb[(size_t)(32+u*5+i)*PVOL];
  const float* T0 = consts + 0;
  const float* T1 = consts + 9;
  const float* T2 = consts + 36;
  float i0=0.f, i1[3]={0,0,0}, i2[5]={0,0,0,0,0};
  for(int i=0;i<3;++i) for(int jj=0;jj<3;++jj){
    float vij = vv[i]*vv[jj];
    i0 += T0[i*3+jj]*vij;
    for(int a=0;a<3;++a) i1[a] += T1[(a*3+i)*3+jj]*vij;
    for(int a=0;a<5;++a) i2[a] += T2[(a*3+i)*3+jj]*vij;
  }
  size_t base_b = ((size_t)b*26 + (xi+3))*2;
  size_t pos = ((size_t)(yi+3))*26 + (zi+3);
  auto wr = [&](int ci, float v){
    int h = ci>=80 ? 1 : 0; int cl = ci - 80*h;
    XB[(base_b + h)*XB_SLICE + pos*96 + cl] = f2bf(v);
  };
  wr(u, s);
  wr(8+u, i0);
  for(int i=0;i<3;++i) wr(16+u*3+i, vv[i]);
  for(int a=0;a<3;++a) wr(40+u*3+a, i1[a]);
  for(int i=0;i<5;++i) wr(64+u*5+i, qq[i]);
  for(int a=0;a<5;++a) wr(104+u*5+a, i2[a]);
}

// ---------------- kernel 4: build K (one block per tap, LDS-staged w+basis) ----------------
// KB[tap][half][ks][co80][kk32]
__global__ __launch_bounds__(256) void build_K_kernel(WPtrs W,
    const float* __restrict__ consts, u16* __restrict__ KB){
  int tap = blockIdx.x, tid = threadIdx.x;
  __shared__ float ws[7296];
  __shared__ float bs[777];
  for(int p=0;p<9;++p){
    int n = 384*NL_P[p];
    const float* wp = W.p[p];
    for(int e=tid; e<n; e+=256) ws[WSOFF[p]+e] = wp[e];
  }
  for(int f=tid; f<777; f+=256) bs[f] = consts[OFF_BASIS + f*343 + tap];
  __syncthreads();
  for(int o=tid; o<15360; o+=256){
    int kk = o&31;
    int co = (o>>5)%80;
    int ks = (o/2560)%3;
    int half = o/7680;
    int ci_l = ks*32 + kk;
    float acc = 0.f;
    bool valid = (co<72) && (half==0 ? (ci_l<80) : (ci_l<64));
    if(valid){
      int ci = half*80 + ci_l;
      int lo,u,a;
      if(co<8){ lo=0; u=co; a=0; }
      else if(co<32){ lo=1; u=(co-8)/3; a=(co-8)%3; }
      else { lo=2; u=(co-32)/5; a=(co-32)%5; }
      int li,vv,i;
      if(ci<16){ li=0; vv=ci; i=0; }
      else if(ci<64){ li=1; vv=(ci-16)/3; i=(ci-16)%3; }
      else { li=2; vv=(ci-64)/5; i=(ci-64)%5; }
      int p = lo*3+li;
      int nl = NL_P[p];
      int A = 2*lo+1, I = 2*li+1;
      const float* wb = ws + WSOFF[p] + (u*16+vv)*nl*3;
      const float* bb = bs + BSOFF[p];
      for(int lk=0; lk<nl; ++lk)
        for(int j=0;j<3;++j)
          acc = fmaf(wb[lk*3+j], bb[((lk*3+j)*A + a)*I + i], acc);
    }
    KB[(size_t)tap*15360 + o] = f2bf(acc);
  }
}

// ---------------- kernel 5: MFMA implicit-GEMM conv, depth-3 software pipeline ----------------
// 1D grid 240 = (20 xo, 6 dx-groups, 2 b), XCD-chunked swizzle (240 = 8*30).
#define RS 104   // LDS row stride (ushorts)
#define MF(a,b,c) __builtin_amdgcn_mfma_f32_16x16x32_bf16(a,b,c,0,0,0)

struct Frag { bf16x8 a0,a1,a2,a3,a4, b0,b1,b2,b3; };

#define LOADSTEP(F, s) { \
  int t_ = (s)/KS; int ks_ = (s) - t_*KS; \
  int code_ = tl[t_]; int dy_ = code_>>4, dz_ = code_&15; \
  const u16* ka_ = KB + ((size_t)((dx*49+dy_*7+dz_)*2+half))*7680 + ks_*2560 + lrow*32 + lseg*8; \
  F.a0 = *(const bf16x8*)(ka_);       \
  F.a1 = *(const bf16x8*)(ka_+512);   \
  F.a2 = *(const bf16x8*)(ka_+1024);  \
  F.a3 = *(const bf16x8*)(ka_+1536);  \
  F.a4 = *(const bf16x8*)(ka_+2048);  \
  int rb_ = dy_*26+dz_; \
  const u16* bp_ = Bl + ks_*32 + lseg*8; \
  F.b0 = *(const bf16x8*)(bp_ + (row0_0+rb_)*RS); \
  F.b1 = *(const bf16x8*)(bp_ + (row0_1+rb_)*RS); \
  F.b2 = *(const bf16x8*)(bp_ + (row0_2+rb_)*RS); \
  F.b3 = *(const bf16x8*)(bp_ + (row0_3+rb_)*RS); \
}

#define DOF(F,bf,fi) \
  acc[0][fi]=MF(F.a0,F.bf,acc[0][fi]); \
  acc[1][fi]=MF(F.a1,F.bf,acc[1][fi]); \
  acc[2][fi]=MF(F.a2,F.bf,acc[2][fi]); \
  acc[3][fi]=MF(F.a3,F.bf,acc[3][fi]); \
  acc[4][fi]=MF(F.a4,F.bf,acc[4][fi]);

#define DOSTEP(F) { \
  __builtin_amdgcn_s_setprio(1); \
  DOF(F,b0,0) DOF(F,b1,1) DOF(F,b2,2) \
  if(NF==4){ DOF(F,b3,3) } \
  __builtin_amdgcn_s_setprio(0); \
}

__global__ __launch_bounds__(512) void conv_mfma(const u16* __restrict__ XB,
    const u16* __restrict__ KB, float* __restrict__ y){
  __shared__ __align__(16) u16 Bl[676*RS];   // 140,608 B
  int wg = blockIdx.x;
  int swz = (wg & 7)*30 + (wg >> 3);   // XCD-chunked, bijective (240 = 8*30)
  int xo = swz % 20; int g = (swz/20) % 6; int b = swz/120;
  int tid = threadIdx.x;
  int w = tid>>6, l = tid&63, lrow = l&15, lseg = l>>4;
  int nf0 = (w<7)? w*3 : 21;
  int NF  = (w<7)? 3 : 4;
  f32x4 acc[5][4];
  #pragma unroll
  for(int mf=0;mf<5;++mf)
    #pragma unroll
    for(int f=0;f<4;++f) acc[mf][f] = (f32x4){0.f,0.f,0.f,0.f};
  int row0_0, row0_1, row0_2, row0_3;
  { int n;
    n=(nf0+0)*16+lrow; row0_0=(n/20)*26+(n%20);
    n=(nf0+1)*16+lrow; row0_1=(n/20)*26+(n%20);
    n=(nf0+2)*16+lrow; row0_2=(n/20)*26+(n%20);
    n=(nf0+3)*16+lrow; row0_3=(n/20)*26+(n%20); }

  int ndx = (g==0)? 2 : 1;
  for(int id=0; id<ndx; ++id){
    int dx = (g==0)? id*6 : g;
    const unsigned char* tl; int nt;
    if(dx==0 || dx==6){ tl = TAP_S; nt = 9; }
    else if(dx==1 || dx==5){ tl = TAP_M; nt = 25; }
    else { tl = TAP_B; nt = 37; }
    for(int half=0; half<2; ++half){
      __syncthreads();
      const u16* src = XB + ((size_t)(b*26 + xo + dx)*2 + half)*XB_SLICE;
      for(int c=tid; c<8112; c+=512){
        ulonglong2 v = ((const ulonglong2*)src)[c];
        int row = c/12, wi = c - row*12;
        *(ulonglong2*)(Bl + row*RS + wi*8) = v;
      }
      __syncthreads();
      const int KS = 3-half;      // half1 ks2 is all-zero padding: skip
      int nsteps = nt*KS;         // >= 18 always
      Frag F0, F1, F2;
      LOADSTEP(F0, 0);
      LOADSTEP(F1, 1);
      int s = 0;
      while(true){
        if(s+2<nsteps) LOADSTEP(F2, s+2);
        DOSTEP(F0);
        if(++s >= nsteps) break;
        if(s+2<nsteps) LOADSTEP(F0, s+2);
        DOSTEP(F1);
        if(++s >= nsteps) break;
        if(s+2<nsteps) LOADSTEP(F1, s+2);
        DOSTEP(F2);
        if(++s >= nsteps) break;
      }
    }
  }
  // epilogue: atomic combine across the 6 dx-groups. C/D: col=lane&15 (n), row=(lane>>4)*4+r (co)
  #pragma unroll
  for(int f=0; f<4; ++f){
    if(f < NF){
      int n = (nf0+f)*16 + lrow;
      #pragma unroll
      for(int mf=0; mf<5; ++mf){
        #pragma unroll
        for(int r=0; r<4; ++r){
          int co = mf*16 + lseg*4 + r;
          if(co < 72)
            atomicAdd(&y[((size_t)(b*COUT+co)*20 + xo)*400 + n], acc[mf][f][r]);
        }
      }
    }
  }
}

// ---------------- kernel 6: bn partial sums (grid 24 x 16, atomic combine) ----------------
__global__ __launch_bounds__(256) void bn_partial_kernel(const float* __restrict__ y,
    float* __restrict__ stats){
  int g = blockIdx.x, chunk = blockIdx.y, tid = threadIdx.x;
  int ch0, nc;
  if(g<8){ ch0=g; nc=1; }
  else if(g<16){ ch0=8+(g-8)*3; nc=3; }
  else { ch0=32+(g-16)*5; nc=5; }
  float s=0.f;
  int lo = chunk*1000, hi = lo+1000;      // over 2*PVOL = 16000 positions
  for(int idx=lo+tid; idx<hi; idx+=256){
    int b = idx/PVOL, p = idx%PVOL;
    const float* yb = y + ((size_t)b*COUT + ch0)*PVOL + p;
    for(int c=0;c<nc;++c){ float v = yb[(size_t)c*PVOL]; s += v*v; }
  }
  __shared__ float red[256];
  red[tid]=s; __syncthreads();
  for(int st=128; st>0; st>>=1){ if(tid<st) red[tid]+=red[tid+st]; __syncthreads(); }
  if(tid==0) atomicAdd(&stats[g], red[0]);
}

// ---------------- kernel 7: apply scale/bias/relu ----------------
__global__ __launch_bounds__(256) void apply_kernel(float* __restrict__ y,
    const float* __restrict__ stats, const float* __restrict__ gamma,
    const float* __restrict__ bias){
  int id = blockIdx.x*256 + threadIdx.x;
  if(id >= 2*COUT*PVOL) return;
  int c = (id/PVOL)%COUT;
  int g = (c<8)? c : ((c<32)? 8+(c-8)/3 : 16+(c-32)/5);
  float scale = gamma[g]*rsqrtf(stats[g]*(1.f/16000.f) + 1e-5f);
  float val = y[id]*scale;
  if(c<8) val = fmaxf(val + bias[c], 0.f);
  y[id] = val;
}

// ---------------- launch ----------------
extern "C" void kernel_launch(void* const* d_in, const int* in_sizes, int n_in,
                              void* d_out, int out_size, void* d_ws, size_t ws_size,
                              hipStream_t stream){
  const float* x = (const float*)d_in[0];
  WPtrs W;
  for(int k=0;k<9;++k) W.p[k] = (const float*)d_in[1+k];
  const float* gamma = (const float*)d_in[10];
  const float* bias  = (const float*)d_in[11];
  char* base = (char*)d_ws;
  float* consts = (float*)base;
  u16* XB = (u16*)(base + OFF_XB_BYTES);
  u16* KB = (u16*)(base + OFF_KB_BYTES);
  float* stats = (float*)(base + OFF_STATS_BYTES);
  float* y = (float*)d_out;

  hipMemsetAsync(XB, 0, XB_BYTES, stream);
  hipMemsetAsync(y, 0, (size_t)2*COUT*PVOL*sizeof(float), stream);
  hipMemsetAsync(stats, 0, 24*sizeof(float), stream);
  gen_all_kernel<<<58,256,0,stream>>>(consts);
  build_xin_kernel<<<(2*MCH*PVOL+255)/256,256,0,stream>>>(x, consts, XB);
  build_K_kernel<<<343,256,0,stream>>>(W, consts, KB);
  conv_mfma<<<240,512,0,stream>>>(XB, KB, y);
  bn_partial_kernel<<<dim3(24,16),256,0,stream>>>(y, stats);
  apply_kernel<<<(2*COUT*PVOL+255)/256,256,0,stream>>>(y, stats, gamma, bias);
}